// Round 1
// baseline (41.133 us; speedup 1.0000x reference)
//
#include <hip/hip_runtime.h>

// 3D MRoPE cos/sin table builder.
// Output: cos [131072,192] fp32 then sin [131072,192] fp32, flat-concatenated.
// Structure: row p = t*4096 + y*64 + x (T=32,H=64,W=64).
//   d in [0,64):    f = t * inv_freq_t[d & 31]
//   d in [64,128):  f = y * inv_freq_y[(d-64) & 31]
//   d in [128,192): f = x * inv_freq_x[(d-128) & 31]
// cos/sin of f. Only (32+64+64)*64 = 10240 unique values per table (80 KB both).

#define T_FRAMES 32
#define HGT 64
#define WID 64
#define NPOS (T_FRAMES * HGT * WID)  // 131072
#define DIMC 192
#define TAB_FLOATS 10240             // per table (cos or sin)

// d_ws float layout:
//   cos table: [0,2048) t-part (32 rows x 64), [2048,6144) y-part, [6144,10240) x-part
//   sin table: same layout at +10240
__global__ void mrope_build_tables(const float* __restrict__ ift,
                                   const float* __restrict__ ify,
                                   const float* __restrict__ ifx,
                                   float* __restrict__ ws) {
    int i = blockIdx.x * blockDim.x + threadIdx.x;
    float* wc = ws;
    float* wn = ws + TAB_FLOATS;
    if (i < 1024) {                 // t: 32 pos x 32 freqs
        int p = i >> 5, j = i & 31;
        float s, c;
        sincosf((float)p * ift[j], &s, &c);
        int b = p * 64 + j;
        wc[b] = c; wc[b + 32] = c;  // duplicated feature halves
        wn[b] = s; wn[b + 32] = s;
    } else if (i < 3072) {          // y: 64 pos x 32 freqs
        int k = i - 1024; int p = k >> 5, j = k & 31;
        float s, c;
        sincosf((float)p * ify[j], &s, &c);
        int b = 2048 + p * 64 + j;
        wc[b] = c; wc[b + 32] = c;
        wn[b] = s; wn[b + 32] = s;
    } else if (i < 5120) {          // x: 64 pos x 32 freqs
        int k = i - 3072; int p = k >> 5, j = k & 31;
        float s, c;
        sincosf((float)p * ifx[j], &s, &c);
        int b = 6144 + p * 64 + j;
        wc[b] = c; wc[b + 32] = c;
        wn[b] = s; wn[b + 32] = s;
    }
}

// Main writer: one float4 of cos + one float4 of sin per loop step.
// v = float4 index within the cos output. 48 float4 per row; segment (16
// float4) boundaries are float4-aligned, so each float4 comes from one table.
__global__ void mrope_write(const float* __restrict__ ws, float* __restrict__ out) {
    const int totalv = NPOS * DIMC / 4;  // 6291456
    const float4* __restrict__ wc = (const float4*)ws;
    const float4* __restrict__ wn = (const float4*)(ws + TAB_FLOATS);
    float4* __restrict__ oc = (float4*)out;
    float4* __restrict__ os = (float4*)(out + (size_t)NPOS * DIMC);
    int stride = gridDim.x * blockDim.x;
    for (int v = blockIdx.x * blockDim.x + threadIdx.x; v < totalv; v += stride) {
        int p  = v / 48;             // row (magic-mul)
        int dv = v - p * 48;         // float4 index within row [0,48)
        int seg = dv >> 4;           // 0=t,1=y,2=x
        int t = p >> 12;
        int y = (p >> 6) & 63;
        int x = p & 63;
        int c, base;                 // base in float4 units
        if (seg == 0)      { c = t; base = 0;    }
        else if (seg == 1) { c = y; base = 512;  }   // 2048/4
        else               { c = x; base = 1536; }   // 6144/4
        int idx = base + c * 16 + (dv & 15);
        oc[v] = wc[idx];
        os[v] = wn[idx];
    }
}

// Fallback (only if ws_size < 80 KB): direct per-element sincos.
__global__ void mrope_direct(const float* __restrict__ ift,
                             const float* __restrict__ ify,
                             const float* __restrict__ ifx,
                             float* __restrict__ out) {
    const long long total = (long long)NPOS * DIMC;
    long long stride = (long long)gridDim.x * blockDim.x;
    for (long long e = blockIdx.x * (long long)blockDim.x + threadIdx.x; e < total; e += stride) {
        int p = (int)(e / DIMC);
        int d = (int)(e - (long long)p * DIMC);
        int t = p >> 12, y = (p >> 6) & 63, x = p & 63;
        float coord; const float* invf; int j;
        if (d < 64)       { coord = (float)t; invf = ift; j = d & 31; }
        else if (d < 128) { coord = (float)y; invf = ify; j = (d - 64) & 31; }
        else              { coord = (float)x; invf = ifx; j = (d - 128) & 31; }
        float s, c;
        sincosf(coord * invf[j], &s, &c);
        out[e] = c;
        out[e + (long long)NPOS * DIMC] = s;
    }
}

extern "C" void kernel_launch(void* const* d_in, const int* in_sizes, int n_in,
                              void* d_out, int out_size, void* d_ws, size_t ws_size,
                              hipStream_t stream) {
    const float* ift = (const float*)d_in[1];
    const float* ify = (const float*)d_in[2];
    const float* ifx = (const float*)d_in[3];
    float* out = (float*)d_out;

    if (ws_size >= 2 * TAB_FLOATS * sizeof(float)) {
        float* ws = (float*)d_ws;
        mrope_build_tables<<<20, 256, 0, stream>>>(ift, ify, ifx, ws);
        // 2048 blocks x 256 threads, grid-stride (12 float4-pairs per thread)
        mrope_write<<<2048, 256, 0, stream>>>(ws, out);
    } else {
        mrope_direct<<<2048, 256, 0, stream>>>(ift, ify, ifx, out);
    }
}

// Round 2
// 40.147 us; speedup vs baseline: 1.0246x; 1.0246x over previous
//
#include <hip/hip_runtime.h>

// 3D MRoPE cos/sin table builder — fused single kernel, direct trig.
// Output: cos [131072,192] fp32 then sin [131072,192] fp32, flat.
// Row p = t*4096 + y*64 + x (T=32, H=64, W=64).
//   d in [0,64):    angle = t * inv_freq_t[d & 31]
//   d in [64,128):  angle = y * inv_freq_y[(d-64) & 31]
//   d in [128,192): angle = x * inv_freq_x[(d-128) & 31]
// Pure streaming-write problem (201.3 MB out, ~128 B in). Trig via fast
// hardware v_sin_f32/v_cos_f32 (max |angle| = 63 rad ~ 10 revolutions, in
// range; abs err ~1e-5 << 2e-2 threshold). Nontemporal stores: output >> L2.

#define T_FRAMES 32
#define HGT 64
#define WID 64
#define NPOS (T_FRAMES * HGT * WID)  // 131072
#define DIMC 192

typedef float f4v __attribute__((ext_vector_type(4)));

__global__ __launch_bounds__(256) void mrope_fused(
    const float* __restrict__ ift,
    const float* __restrict__ ify,
    const float* __restrict__ ifx,
    float* __restrict__ out)
{
    const int totalv = NPOS * DIMC / 4;  // 6,291,456 float4 per table
    f4v* __restrict__ oc = (f4v*)out;
    f4v* __restrict__ os = (f4v*)(out + (size_t)NPOS * DIMC);
    const int stride = gridDim.x * blockDim.x;
    // 2048 blocks x 256 threads = 524,288 threads -> exactly 12 iters, no tail.
    for (int v = blockIdx.x * blockDim.x + threadIdx.x; v < totalv; v += stride) {
        int p  = v / 48;                 // row (compiler magic-mul)
        int dv = v - p * 48;             // float4 index within row [0,48)
        int seg = dv >> 4;               // 0=t, 1=y, 2=x (16 float4 each)
        int coord; const float* invf;
        if (seg == 0)      { coord = p >> 12;       invf = ift; }
        else if (seg == 1) { coord = (p >> 6) & 63; invf = ify; }
        else               { coord = p & 63;        invf = ifx; }
        // d = dv*4+k - seg*64; j = d & 31 = (dv&7)*4 + k (k=0..3, no wrap).
        f4v fr = ((const f4v*)invf)[dv & 7];   // 16B L1-resident load
        float cf = (float)coord;
        float a0 = cf * fr.x, a1 = cf * fr.y, a2 = cf * fr.z, a3 = cf * fr.w;
        f4v vc, vs;
        vc.x = __cosf(a0); vc.y = __cosf(a1); vc.z = __cosf(a2); vc.w = __cosf(a3);
        vs.x = __sinf(a0); vs.y = __sinf(a1); vs.z = __sinf(a2); vs.w = __sinf(a3);
        __builtin_nontemporal_store(vc, &oc[v]);
        __builtin_nontemporal_store(vs, &os[v]);
    }
}

extern "C" void kernel_launch(void* const* d_in, const int* in_sizes, int n_in,
                              void* d_out, int out_size, void* d_ws, size_t ws_size,
                              hipStream_t stream) {
    // d_in[0] = x (unused); [1]=inv_freq_t, [2]=inv_freq_y, [3]=inv_freq_x
    const float* ift = (const float*)d_in[1];
    const float* ify = (const float*)d_in[2];
    const float* ifx = (const float*)d_in[3];
    mrope_fused<<<2048, 256, 0, stream>>>(ift, ify, ifx, (float*)d_out);
}

// Round 3
// 34.308 us; speedup vs baseline: 1.1990x; 1.1702x over previous
//
#include <hip/hip_runtime.h>

// 3D MRoPE cos/sin table builder — fused single kernel, direct trig.
// Output: cos [131072,192] fp32 then sin [131072,192] fp32, flat.
// Row p = t*4096 + y*64 + x (T=32, H=64, W=64).
//   d in [0,64):    angle = t * inv_freq_t[d & 31]
//   d in [64,128):  angle = y * inv_freq_y[(d-64) & 31]
//   d in [128,192): angle = x * inv_freq_x[(d-128) & 31]
// Pure streaming-write problem (201.3 MB out). R2 A/B: PLAIN stores (vs
// nontemporal) — fillBuffer hits 6.87 TB/s with cached stores; NT bypasses
// L2 write-aggregation and measured only 5.0 TB/s.
// Grid-stride chosen as a multiple of 48 (1536 blocks x 256 = 393216 =
// 48*8192) so each thread's within-row position dv — and hence seg and the
// inv_freq float4 — are loop-invariant; p advances by 8192/iter, 16 iters
// exactly, no tail.

#define T_FRAMES 32
#define HGT 64
#define WID 64
#define NPOS (T_FRAMES * HGT * WID)  // 131072
#define DIMC 192
#define NTHREADS (1536 * 256)        // 393216 = 48 * 8192
#define ITERS 16                     // 6291456 / 393216

typedef float f4v __attribute__((ext_vector_type(4)));

__global__ __launch_bounds__(256) void mrope_fused(
    const float* __restrict__ ift,
    const float* __restrict__ ify,
    const float* __restrict__ ifx,
    float* __restrict__ out)
{
    f4v* __restrict__ oc = (f4v*)out;
    f4v* __restrict__ os = (f4v*)(out + (size_t)NPOS * DIMC);

    const int v0 = blockIdx.x * blockDim.x + threadIdx.x;
    const int dv = v0 % 48;          // float4 index within row — loop-invariant
    int p       = v0 / 48;           // row; advances by 8192 per iteration
    const int seg = dv >> 4;         // 0=t, 1=y, 2=x — loop-invariant

    // j = (dv & 7) * 4 + k (k=0..3): one 16B L1-resident load, hoisted.
    const float* invf = (seg == 0) ? ift : (seg == 1) ? ify : ifx;
    const f4v fr = ((const f4v*)invf)[dv & 7];

    int v = v0;
    #pragma unroll 4
    for (int k = 0; k < ITERS; ++k) {
        int coord;
        if (seg == 0)      coord = p >> 12;        // t (changes by 2/iter)
        else if (seg == 1) coord = (p >> 6) & 63;  // y (invariant: 8192%4096==0 pattern)
        else               coord = p & 63;         // x (invariant)
        float cf = (float)coord;
        float a0 = cf * fr.x, a1 = cf * fr.y, a2 = cf * fr.z, a3 = cf * fr.w;
        f4v vc, vs;
        vc.x = __cosf(a0); vc.y = __cosf(a1); vc.z = __cosf(a2); vc.w = __cosf(a3);
        vs.x = __sinf(a0); vs.y = __sinf(a1); vs.z = __sinf(a2); vs.w = __sinf(a3);
        oc[v] = vc;                  // plain cached stores (R2 A/B vs NT)
        os[v] = vs;
        v += NTHREADS;
        p += NTHREADS / 48;          // 8192
    }
}

extern "C" void kernel_launch(void* const* d_in, const int* in_sizes, int n_in,
                              void* d_out, int out_size, void* d_ws, size_t ws_size,
                              hipStream_t stream) {
    // d_in[0] = x (unused); [1]=inv_freq_t, [2]=inv_freq_y, [3]=inv_freq_x
    const float* ift = (const float*)d_in[1];
    const float* ify = (const float*)d_in[2];
    const float* ifx = (const float*)d_in[3];
    mrope_fused<<<1536, 256, 0, stream>>>(ift, ify, ifx, (float*)d_out);
}